// Round 1
// baseline (58.769 us; speedup 1.0000x reference)
//
#include <hip/hip_runtime.h>

#define NB   256   // N images
#define DOT  512   // points per image
#define HC   16
#define WC   128

__global__ __launch_bounds__(256) void gen_kernel(const float* __restrict__ x,
                                                  const float* __restrict__ W,
                                                  float* __restrict__ out) {
    __shared__ float acc[HC * WC];   // 2048 floats = 8 KB
    const int n   = blockIdx.x;
    const int tid = threadIdx.x;
    const float xn = x[n];

    // zero accumulator: 2048 / 256 = 8 per thread
    #pragma unroll
    for (int i = 0; i < 8; ++i) acc[tid + i * 256] = 0.0f;
    __syncthreads();

    // scatter: each thread handles 2 points
    #pragma unroll
    for (int pp = 0; pp < 2; ++pp) {
        const int d = tid + pp * 256;
        const float2 w2 = ((const float2*)W)[d];           // W[2d], W[2d+1]
        const float px = (tanhf(xn * w2.x) * 0.5f + 0.5f) * (float)WC;  // in (0,128)
        const float py = (tanhf(xn * w2.y) * 0.5f + 0.5f) * (float)HC;  // in (0,16)
        const int wc0 = (int)px;
        const int hc0 = (int)py;
        #pragma unroll
        for (int dh = -1; dh <= 1; ++dh) {
            const int h = hc0 + dh;
            if (h < 0 || h >= HC) continue;
            const float fy = (float)h - py;
            #pragma unroll
            for (int dw = -1; dw <= 1; ++dw) {
                const int w = wc0 + dw;
                if (w < 0 || w >= WC) continue;
                const float fx = (float)w - px;
                const float d2 = fx * fx + fy * fy;
                if (d2 < 1.0f) {
                    const float val = (1.0f - sqrtf(d2)) * 3.0f;
                    atomicAdd(&acc[h * WC + w], val);
                }
            }
        }
    }
    __syncthreads();

    // epilogue: tanh(acc)*2-1, float4-vectorized; 512 float4 per image
    float4* o4 = (float4*)(out + n * (HC * WC));
    const float4* a4 = (const float4*)acc;
    #pragma unroll
    for (int v = 0; v < 2; ++v) {
        const int idx = tid + v * 256;
        float4 a = a4[idx];
        float4 r;
        r.x = tanhf(a.x) * 2.0f - 1.0f;
        r.y = tanhf(a.y) * 2.0f - 1.0f;
        r.z = tanhf(a.z) * 2.0f - 1.0f;
        r.w = tanhf(a.w) * 2.0f - 1.0f;
        o4[idx] = r;
    }
}

extern "C" void kernel_launch(void* const* d_in, const int* in_sizes, int n_in,
                              void* d_out, int out_size, void* d_ws, size_t ws_size,
                              hipStream_t stream) {
    const float* x = (const float*)d_in[0];   // [N,1,1] f32
    const float* W = (const float*)d_in[1];   // [1024,1] f32
    float* out = (float*)d_out;               // [N,1,16,128] f32
    gen_kernel<<<NB, 256, 0, stream>>>(x, W, out);
}

// Round 2
// 57.997 us; speedup vs baseline: 1.0133x; 1.0133x over previous
//
#include <hip/hip_runtime.h>

#define NB      256   // N images
#define DOT     512   // points per image
#define HC      16
#define WC      128
#define CELLS   (HC * WC)        // 2048
#define NREP    4                // accumulator replicas (kills same-address atomic serialization)
#define RSTRIDE (CELLS + 8)      // +8 floats: replica r shifted by 8r banks; 8224*4B stays 16B-aligned

// tanh(v) = 1 - 2/(exp(2v)+1); v_exp_f32 + v_rcp_f32. Exact ±1 at saturation.
__device__ __forceinline__ float fast_tanh(float v) {
    float e = __expf(2.0f * v);
    return 1.0f - 2.0f * __builtin_amdgcn_rcpf(e + 1.0f);
}

__global__ __launch_bounds__(512) void gen_kernel(const float* __restrict__ x,
                                                  const float* __restrict__ W,
                                                  float* __restrict__ out) {
    __shared__ float acc[NREP * RSTRIDE];   // ~32.9 KB
    const int n   = blockIdx.x;
    const int tid = threadIdx.x;
    const float xn = x[n];

    // zero all replicas
    for (int i = tid; i < NREP * RSTRIDE; i += 512) acc[i] = 0.0f;
    __syncthreads();

    // one point per thread: weight>0 iff dis<1, i.e. only the 3x3 cell
    // neighborhood of (int(px), int(py)) can receive a contribution.
    const float2 w2 = ((const float2*)W)[tid];          // W[2*tid], W[2*tid+1]
    const float px = (fast_tanh(xn * w2.x) * 0.5f + 0.5f) * (float)WC;  // [0,128]
    const float py = (fast_tanh(xn * w2.y) * 0.5f + 0.5f) * (float)HC;  // [0,16]
    const int wc0 = (int)px;
    const int hc0 = (int)py;
    float* myacc = acc + (tid & (NREP - 1)) * RSTRIDE;
    #pragma unroll
    for (int dh = -1; dh <= 1; ++dh) {
        const int h = hc0 + dh;
        if (h < 0 || h >= HC) continue;
        const float fy = (float)h - py;
        #pragma unroll
        for (int dw = -1; dw <= 1; ++dw) {
            const int w = wc0 + dw;
            if (w < 0 || w >= WC) continue;
            const float fx = (float)w - px;
            const float d2 = fx * fx + fy * fy;
            if (d2 < 1.0f) {
                atomicAdd(&myacc[h * WC + w], (1.0f - sqrtf(d2)) * 3.0f);
            }
        }
    }
    __syncthreads();

    // epilogue: 4 cells (one float4) per thread; sum replicas, tanh, store
    const int c = tid * 4;
    const float4 a0 = *(const float4*)&acc[0 * RSTRIDE + c];
    const float4 a1 = *(const float4*)&acc[1 * RSTRIDE + c];
    const float4 a2 = *(const float4*)&acc[2 * RSTRIDE + c];
    const float4 a3 = *(const float4*)&acc[3 * RSTRIDE + c];
    float4 r;
    r.x = fast_tanh(a0.x + a1.x + a2.x + a3.x) * 2.0f - 1.0f;
    r.y = fast_tanh(a0.y + a1.y + a2.y + a3.y) * 2.0f - 1.0f;
    r.z = fast_tanh(a0.z + a1.z + a2.z + a3.z) * 2.0f - 1.0f;
    r.w = fast_tanh(a0.w + a1.w + a2.w + a3.w) * 2.0f - 1.0f;
    ((float4*)(out + n * CELLS))[tid] = r;
}

extern "C" void kernel_launch(void* const* d_in, const int* in_sizes, int n_in,
                              void* d_out, int out_size, void* d_ws, size_t ws_size,
                              hipStream_t stream) {
    const float* x = (const float*)d_in[0];   // [N,1,1] f32
    const float* W = (const float*)d_in[1];   // [1024,1] f32
    float* out = (float*)d_out;               // [N,1,16,128] f32
    gen_kernel<<<NB, 512, 0, stream>>>(x, W, out);
}